// Round 3
// baseline (346.378 us; speedup 1.0000x reference)
//
#include <hip/hip_runtime.h>

typedef __bf16 bf16;
typedef __bf16 bf16x4 __attribute__((ext_vector_type(4)));
typedef __bf16 bf16x8 __attribute__((ext_vector_type(8)));
typedef float floatx4 __attribute__((ext_vector_type(4)));

#define EPS 1.1920929e-07f
// q scale = D^-0.5 * log2(e) folded together (D=64 -> 0.125)
#define QSCALE (0.125f * 1.44269504088896f)
// fixed softmax shift: |q_eff . k| <= ||q_eff||*||k|| = (8*QSCALE)*8 = 11.5416
#define SHIFT_C 11.5416f

__device__ __forceinline__ floatx4 mfma16(bf16x8 a, bf16x8 b, floatx4 c) {
  return __builtin_amdgcn_mfma_f32_16x16x32_bf16(a, b, c, 0, 0, 0);
}

// ---------------- prep kernels ----------------
__global__ void cast_x_kernel(const float* __restrict__ x, bf16* __restrict__ xb) {
  int i = (blockIdx.x * blockDim.x + threadIdx.x) * 4;
  float4 v = *(const float4*)(x + i);
  bf16x4 o = {(bf16)v.x, (bf16)v.y, (bf16)v.z, (bf16)v.w};
  *(bf16x4*)(xb + i) = o;
}

// Wqkv_t[n][k] (n<1024: Wq col n; n<1280: Wk col n-1024; else Wv col n-1280), bf16
__global__ void pack_wqkv_kernel(const float* __restrict__ Wq, const float* __restrict__ Wk,
                                 const float* __restrict__ Wv, bf16* __restrict__ out) {
  __shared__ float tile[32][33];
  int n0 = blockIdx.x * 32, k0 = blockIdx.y * 32;
  int tx = threadIdx.x & 31, ty = threadIdx.x >> 5;
#pragma unroll
  for (int i = 0; i < 4; i++) {
    int k = k0 + ty + i * 8, n = n0 + tx;
    float v;
    if (n < 1024)      v = Wq[(size_t)k * 1024 + n];
    else if (n < 1280) v = Wk[(size_t)k * 256 + (n - 1024)];
    else               v = Wv[(size_t)k * 256 + (n - 1280)];
    tile[ty + i * 8][tx] = v;
  }
  __syncthreads();
#pragma unroll
  for (int i = 0; i < 4; i++) {
    int n = n0 + ty + i * 8, k = k0 + tx;
    out[(size_t)n * 1024 + k] = (bf16)tile[tx][ty + i * 8];
  }
}

__global__ void trans_wproj_kernel(const float* __restrict__ W, bf16* __restrict__ out) {
  __shared__ float tile[32][33];
  int n0 = blockIdx.x * 32, k0 = blockIdx.y * 32;
  int tx = threadIdx.x & 31, ty = threadIdx.x >> 5;
#pragma unroll
  for (int i = 0; i < 4; i++)
    tile[ty + i * 8][tx] = W[(size_t)(k0 + ty + i * 8) * 1024 + n0 + tx];
  __syncthreads();
#pragma unroll
  for (int i = 0; i < 4; i++)
    out[(size_t)(n0 + ty + i * 8) * 1024 + k0 + tx] = (bf16)tile[tx][ty + i * 8];
}

// V [b][kv][s][d] -> Vt [b][kv][d][s], 64x64 LDS tiles
__global__ void trans_v_kernel(const bf16* __restrict__ Vb, bf16* __restrict__ Vt) {
  __shared__ bf16 t[64][65];
  int s0 = blockIdx.x * 64;
  size_t base = (size_t)blockIdx.y * 2048 * 64;
  int tx = threadIdx.x & 63, ty = threadIdx.x >> 6;
#pragma unroll
  for (int i = 0; i < 16; i++) {
    int row = ty * 16 + i;
    t[tx][row] = Vb[base + (size_t)(s0 + row) * 64 + tx];
  }
  __syncthreads();
  size_t obase = (size_t)blockIdx.y * 64 * 2048;
#pragma unroll
  for (int i = 0; i < 16; i++) {
    int d = ty * 16 + i;
    Vt[obase + (size_t)d * 2048 + s0 + tx] = t[d][tx];
  }
}

// ---------------- GEMM: C[M][N] = A[M][K] * Bt[N][K]^T, bf16 in, fp32 acc ----------------
template <bool OUT_BF16>
__global__ __launch_bounds__(256) void gemm_kernel(const bf16* __restrict__ A,
                                                   const bf16* __restrict__ Bt,
                                                   void* __restrict__ Cout,
                                                   int M, int N, int K) {
  __shared__ bf16 As[128 * 40];
  __shared__ bf16 Bs[128 * 40];
  const int tid = threadIdx.x;
  const int m0 = blockIdx.y * 128, n0 = blockIdx.x * 128;
  const int w = tid >> 6, lane = tid & 63;
  const int q = lane >> 4, r0 = lane & 15;
  const int wr2 = w >> 1, wc2 = w & 1;
  const int srow = tid >> 2;
  const int scol = (tid & 3) * 8;

  floatx4 acc[4][4];
#pragma unroll
  for (int i = 0; i < 4; i++)
#pragma unroll
    for (int j = 0; j < 4; j++) acc[i][j] = (floatx4){0.f, 0.f, 0.f, 0.f};

  for (int k0 = 0; k0 < K; k0 += 32) {
    __syncthreads();
#pragma unroll
    for (int i = 0; i < 2; i++) {
      int r = srow + i * 64;
      *(uint4*)&As[r * 40 + scol] = *(const uint4*)(A + (size_t)(m0 + r) * K + k0 + scol);
      *(uint4*)&Bs[r * 40 + scol] = *(const uint4*)(Bt + (size_t)(n0 + r) * K + k0 + scol);
    }
    __syncthreads();
    bf16x8 af[4], bfr[4];
#pragma unroll
    for (int mt = 0; mt < 4; mt++) af[mt] = *(const bf16x8*)&As[(wr2 * 64 + mt * 16 + r0) * 40 + q * 8];
#pragma unroll
    for (int nt = 0; nt < 4; nt++) bfr[nt] = *(const bf16x8*)&Bs[(wc2 * 64 + nt * 16 + r0) * 40 + q * 8];
#pragma unroll
    for (int mt = 0; mt < 4; mt++)
#pragma unroll
      for (int nt = 0; nt < 4; nt++)
        acc[mt][nt] = mfma16(af[mt], bfr[nt], acc[mt][nt]);
  }
#pragma unroll
  for (int mt = 0; mt < 4; mt++)
#pragma unroll
    for (int nt = 0; nt < 4; nt++)
#pragma unroll
      for (int r = 0; r < 4; r++) {
        int row = m0 + wr2 * 64 + mt * 16 + q * 4 + r;
        int col = n0 + wc2 * 64 + nt * 16 + r0;
        float v = acc[mt][nt][r];
        if (OUT_BF16) ((bf16*)Cout)[(size_t)row * N + col] = (bf16)v;
        else          ((float*)Cout)[(size_t)row * N + col] = v;
      }
}

// ---------------- postproc: gate+ve add, RoPE, RMS, layout for attention ----------------
__global__ void postproc_kernel(const bf16* __restrict__ qkv, const float* __restrict__ x,
                                const float* __restrict__ ve, const float* __restrict__ cosb,
                                const float* __restrict__ sinb, const float* __restrict__ wgate,
                                bf16* __restrict__ Qb, bf16* __restrict__ Kb, bf16* __restrict__ Vb) {
  int t = blockIdx.x;
  int b = t >> 11, s = t & 2047;
  int lane = threadIdx.x;

  // gate = 2*sigmoid(x[:,:128] @ Wgate)  (Wgate: [128][4] row-major)
  float g[4];
  const float* xrow = x + (size_t)t * 1024;
  float x0 = xrow[lane], x1 = xrow[64 + lane];
#pragma unroll
  for (int kv = 0; kv < 4; kv++)
    g[kv] = x0 * wgate[lane * 4 + kv] + x1 * wgate[(64 + lane) * 4 + kv];
#pragma unroll
  for (int kv = 0; kv < 4; kv++) {
    float v = g[kv];
    for (int m = 1; m < 64; m <<= 1) v += __shfl_xor(v, m, 64);
    g[kv] = 2.f / (1.f + __expf(-v));
  }

  int d = lane & 31;
  float c = cosb[s * 32 + d], sn = sinb[s * 32 + d];
  float sgn = (lane < 32) ? sn : -sn;
  const bf16* qrow = qkv + (size_t)t * 1536;

  // q heads: rope -> rms -> * (0.125*log2e) (score scale + exp2 conversion folded in)
  for (int h = 0; h < 16; h++) {
    float v = (float)qrow[h * 64 + lane];
    float p = __shfl_xor(v, 32, 64);
    float rv = v * c + p * sgn;
    float ss = rv * rv;
    for (int m = 1; m < 64; m <<= 1) ss += __shfl_xor(ss, m, 64);
    float outq = rv * rsqrtf(ss * (1.f / 64.f) + EPS) * QSCALE;
    Qb[(((size_t)b * 16 + h) * 2048 + s) * 64 + lane] = (bf16)outq;
  }
  // k heads + v (v gets gate*ve, no rope/rms; coalesced [s][d] layout)
  for (int kv = 0; kv < 4; kv++) {
    float v = (float)qrow[1024 + kv * 64 + lane];
    float p = __shfl_xor(v, 32, 64);
    float rv = v * c + p * sgn;
    float ss = rv * rv;
    for (int m = 1; m < 64; m <<= 1) ss += __shfl_xor(ss, m, 64);
    float outk = rv * rsqrtf(ss * (1.f / 64.f) + EPS);
    Kb[(((size_t)b * 4 + kv) * 2048 + s) * 64 + lane] = (bf16)outk;
    float vv = (float)qrow[1280 + kv * 64 + lane] + g[kv] * ve[(size_t)t * 256 + kv * 64 + lane];
    Vb[(((size_t)b * 4 + kv) * 2048 + s) * 64 + lane] = (bf16)vv;
  }
}

// ---------------- flash attention: transposed-S scheme, zero LDS ----------------
// S^T = K·Q^T lands P^T directly in a valid MFMA A-fragment (with the j<->k
// slot mapping k=q*8+jj <-> j = sub*16 + 4q + (jj&3)); V B-frags are two 8B
// loads from Vt[d][s] with the same mapping. Row sums via MFMA against ones.
__global__ __launch_bounds__(256, 4) void attn_kernel(const bf16* __restrict__ Qb,
                                                      const bf16* __restrict__ Kb,
                                                      const bf16* __restrict__ Vt,
                                                      const int* __restrict__ wlp,
                                                      const int* __restrict__ wrp,
                                                      bf16* __restrict__ Yb) {
  const int wl = wlp[0];
  const int wrc = min(wrp[0], 0);  // j<=i+wr && j<=i  ==>  j <= i+min(wr,0)
  const int blk = blockIdx.x;
  const int qc = 31 - (blk & 31);  // reversed: longest blocks launch first
  const int bh = blk >> 5;
  const int b = bh >> 4, h = bh & 15, kvh = (bh & 15) >> 2;
  const int w = threadIdx.x >> 6, lane = threadIdx.x & 63;
  const int q = lane >> 4, r0 = lane & 15;
  const int q0 = qc * 64 + w * 16;

  const bf16* qbase = Qb + (((size_t)b * 16 + h) * 2048 + q0 + r0) * 64;
  bf16x8 aq0 = *(const bf16x8*)(qbase + q * 8);
  bf16x8 aq1 = *(const bf16x8*)(qbase + 32 + q * 8);

  floatx4 Oacc[4];
#pragma unroll
  for (int nt = 0; nt < 4; nt++) Oacc[nt] = (floatx4){0.f, 0.f, 0.f, 0.f};
  floatx4 Lacc = (floatx4){0.f, 0.f, 0.f, 0.f};

  const bf16 onev = (bf16)1.0f;
  const bf16x8 ones = {onev, onev, onev, onev, onev, onev, onev, onev};

  int jlo = max(0, q0 - wl) & ~31;
  int jhi = q0 + 15 + wrc;

  const bf16* kbase = Kb + ((size_t)b * 4 + kvh) * 2048 * 64;
  const bf16* vbase = Vt + ((size_t)b * 4 + kvh) * 64 * 2048;

  for (int j0 = jlo; j0 <= jhi; j0 += 32) {
    // K fragments (A operand: m = j-j0 = r0, k = d)
    const bf16* kp = kbase + (size_t)(j0 + r0) * 64 + q * 8;
    bf16x8 kf00 = *(const bf16x8*)(kp);
    bf16x8 kf01 = *(const bf16x8*)(kp + 32);
    bf16x8 kf10 = *(const bf16x8*)(kp + 1024);
    bf16x8 kf11 = *(const bf16x8*)(kp + 1024 + 32);
    // V fragments (B operand for PV: n = d = nt*16+r0, k-slot jj <-> j mapping)
    bf16x8 vf[4];
#pragma unroll
    for (int nt = 0; nt < 4; nt++) {
      const bf16* vp = vbase + (size_t)(nt * 16 + r0) * 2048 + j0 + 4 * q;
      bf16x4 lo = *(const bf16x4*)vp;
      bf16x4 hi = *(const bf16x4*)(vp + 16);
      vf[nt] = __builtin_shufflevector(lo, hi, 0, 1, 2, 3, 4, 5, 6, 7);
    }

    // St = K·Q^T - SHIFT_C  (C-layout: row = j-j0 = q*4+r (+sub*16), col = i-q0 = r0)
    floatx4 s0 = (floatx4){-SHIFT_C, -SHIFT_C, -SHIFT_C, -SHIFT_C};
    floatx4 s1 = s0;
    s0 = mfma16(kf00, aq0, s0);
    s0 = mfma16(kf01, aq1, s0);
    s1 = mfma16(kf10, aq0, s1);
    s1 = mfma16(kf11, aq1, s1);

    bf16x8 pa;
    if (j0 >= q0 + 15 - wl && j0 + 31 <= q0 + wrc) {
      // interior tile: no masking needed
#pragma unroll
      for (int r = 0; r < 4; r++) {
        pa[r] = (bf16)exp2f(s0[r]);
        pa[4 + r] = (bf16)exp2f(s1[r]);
      }
    } else {
      const int i = q0 + r0;
#pragma unroll
      for (int r = 0; r < 4; r++) {
        int ja = j0 + 4 * q + r, jb = ja + 16;
        bool va = (ja <= i + wrc) && (ja >= i - wl);
        bool vb = (jb <= i + wrc) && (jb >= i - wl);
        pa[r] = va ? (bf16)exp2f(s0[r]) : (bf16)0.f;
        pa[4 + r] = vb ? (bf16)exp2f(s1[r]) : (bf16)0.f;
      }
    }

    // P^T registers ARE the A-fragment for PV; row sums via ones-MFMA
    Lacc = mfma16(pa, ones, Lacc);
#pragma unroll
    for (int nt = 0; nt < 4; nt++) Oacc[nt] = mfma16(pa, vf[nt], Oacc[nt]);
  }

  // Oacc/Lacc C-layout: row i = q0 + q*4 + r, col d = nt*16 + r0
  float inv[4];
#pragma unroll
  for (int r = 0; r < 4; r++) inv[r] = 1.f / Lacc[r];
#pragma unroll
  for (int nt = 0; nt < 4; nt++)
#pragma unroll
    for (int r = 0; r < 4; r++) {
      int i = q0 + q * 4 + r;
      Yb[((size_t)b * 2048 + i) * 1024 + h * 64 + nt * 16 + r0] = (bf16)(Oacc[nt][r] * inv[r]);
    }
}

// ---------------- launch ----------------
extern "C" void kernel_launch(void* const* d_in, const int* in_sizes, int n_in,
                              void* d_out, int out_size, void* d_ws, size_t ws_size,
                              hipStream_t stream) {
  const float* x     = (const float*)d_in[0];
  const float* ve    = (const float*)d_in[1];
  const float* cosb  = (const float*)d_in[2];
  const float* sinb  = (const float*)d_in[3];
  const float* Wq    = (const float*)d_in[4];
  const float* Wk    = (const float*)d_in[5];
  const float* Wv    = (const float*)d_in[6];
  const float* Wproj = (const float*)d_in[7];
  const float* Wgate = (const float*)d_in[8];
  const int* wl      = (const int*)d_in[9];
  const int* wr      = (const int*)d_in[10];

  char* ws = (char*)d_ws;
  bf16* Xb      = (bf16*)(ws);                 //  8,388,608 B: x bf16 [4096][1024]
  bf16* Wqkv_t  = (bf16*)(ws + 8388608);       //  3,145,728 B: [1536][1024]
  bf16* Wproj_t = (bf16*)(ws + 11534336);      //  2,097,152 B: [1024][1024]
  bf16* qkvb    = (bf16*)(ws + 13631488);      // 12,582,912 B: [4096][1536]
  bf16* Qb      = (bf16*)(ws + 26214400);      //  8,388,608 B: [2][16][2048][64]
  bf16* Kb      = (bf16*)(ws + 34603008);      //  2,097,152 B: [2][4][2048][64]
  bf16* Vt      = (bf16*)(ws + 36700160);      //  2,097,152 B: [2][4][64][2048]
  bf16* Yb      = (bf16*)(ws + 38797312);      //  8,388,608 B: [4096][1024]  (total 47,185,920)
  bf16* Vb      = Yb;                          //  2 MB staging inside Yb (dead before attn writes Yb)

  cast_x_kernel<<<4096, 256, 0, stream>>>(x, Xb);
  pack_wqkv_kernel<<<dim3(48, 32), 256, 0, stream>>>(Wq, Wk, Wv, Wqkv_t);
  trans_wproj_kernel<<<dim3(32, 32), 256, 0, stream>>>(Wproj, Wproj_t);
  gemm_kernel<true><<<dim3(12, 32), 256, 0, stream>>>(Xb, Wqkv_t, qkvb, 4096, 1536, 1024);
  postproc_kernel<<<4096, 64, 0, stream>>>(qkvb, x, ve, cosb, sinb, Wgate, Qb, Kb, Vb);
  trans_v_kernel<<<dim3(32, 8), 256, 0, stream>>>(Vb, Vt);
  attn_kernel<<<1024, 256, 0, stream>>>(Qb, Kb, Vt, wl, wr, Yb);
  gemm_kernel<false><<<dim3(8, 32), 256, 0, stream>>>(Yb, Wproj_t, d_out, 4096, 1024, 1024);
}

// Round 4
// 209.019 us; speedup vs baseline: 1.6572x; 1.6572x over previous
//
#include <hip/hip_runtime.h>

typedef __bf16 bf16;
typedef __bf16 bf16x4 __attribute__((ext_vector_type(4)));
typedef __bf16 bf16x8 __attribute__((ext_vector_type(8)));
typedef float floatx4 __attribute__((ext_vector_type(4)));

#define EPS 1.1920929e-07f
// q scale = D^-0.5 * log2(e) folded together (D=64 -> 0.125)
#define QSCALE (0.125f * 1.44269504088896f)
// fixed softmax shift: |q_eff . k| <= ||q_eff||*||k|| = (8*QSCALE)*8 = 11.5416
#define SHIFT_C 11.5416f

__device__ __forceinline__ floatx4 mfma16(bf16x8 a, bf16x8 b, floatx4 c) {
  return __builtin_amdgcn_mfma_f32_16x16x32_bf16(a, b, c, 0, 0, 0);
}

// ---------------- prep kernels ----------------
__global__ void cast_x_kernel(const float* __restrict__ x, bf16* __restrict__ xb) {
  int i = (blockIdx.x * blockDim.x + threadIdx.x) * 4;
  float4 v = *(const float4*)(x + i);
  bf16x4 o = {(bf16)v.x, (bf16)v.y, (bf16)v.z, (bf16)v.w};
  *(bf16x4*)(xb + i) = o;
}

// Wqkv_t[n][k] (n<1024: Wq col n; n<1280: Wk col n-1024; else Wv col n-1280), bf16
__global__ void pack_wqkv_kernel(const float* __restrict__ Wq, const float* __restrict__ Wk,
                                 const float* __restrict__ Wv, bf16* __restrict__ out) {
  __shared__ float tile[32][33];
  int n0 = blockIdx.x * 32, k0 = blockIdx.y * 32;
  int tx = threadIdx.x & 31, ty = threadIdx.x >> 5;
#pragma unroll
  for (int i = 0; i < 4; i++) {
    int k = k0 + ty + i * 8, n = n0 + tx;
    float v;
    if (n < 1024)      v = Wq[(size_t)k * 1024 + n];
    else if (n < 1280) v = Wk[(size_t)k * 256 + (n - 1024)];
    else               v = Wv[(size_t)k * 256 + (n - 1280)];
    tile[ty + i * 8][tx] = v;
  }
  __syncthreads();
#pragma unroll
  for (int i = 0; i < 4; i++) {
    int n = n0 + ty + i * 8, k = k0 + tx;
    out[(size_t)n * 1024 + k] = (bf16)tile[tx][ty + i * 8];
  }
}

__global__ void trans_wproj_kernel(const float* __restrict__ W, bf16* __restrict__ out) {
  __shared__ float tile[32][33];
  int n0 = blockIdx.x * 32, k0 = blockIdx.y * 32;
  int tx = threadIdx.x & 31, ty = threadIdx.x >> 5;
#pragma unroll
  for (int i = 0; i < 4; i++)
    tile[ty + i * 8][tx] = W[(size_t)(k0 + ty + i * 8) * 1024 + n0 + tx];
  __syncthreads();
#pragma unroll
  for (int i = 0; i < 4; i++)
    out[(size_t)(n0 + ty + i * 8) * 1024 + k0 + tx] = (bf16)tile[tx][ty + i * 8];
}

// ---------------- GEMM: C[M][N] = A[M][K] * Bt[N][K]^T, bf16 in, fp32 acc ----------------
template <bool OUT_BF16>
__global__ __launch_bounds__(256) void gemm_kernel(const bf16* __restrict__ A,
                                                   const bf16* __restrict__ Bt,
                                                   void* __restrict__ Cout,
                                                   int M, int N, int K) {
  __shared__ bf16 As[128 * 40];
  __shared__ bf16 Bs[128 * 40];
  const int tid = threadIdx.x;
  const int m0 = blockIdx.y * 128, n0 = blockIdx.x * 128;
  const int w = tid >> 6, lane = tid & 63;
  const int q = lane >> 4, r0 = lane & 15;
  const int wr2 = w >> 1, wc2 = w & 1;
  const int srow = tid >> 2;
  const int scol = (tid & 3) * 8;

  floatx4 acc[4][4];
#pragma unroll
  for (int i = 0; i < 4; i++)
#pragma unroll
    for (int j = 0; j < 4; j++) acc[i][j] = (floatx4){0.f, 0.f, 0.f, 0.f};

  for (int k0 = 0; k0 < K; k0 += 32) {
    __syncthreads();
#pragma unroll
    for (int i = 0; i < 2; i++) {
      int r = srow + i * 64;
      *(uint4*)&As[r * 40 + scol] = *(const uint4*)(A + (size_t)(m0 + r) * K + k0 + scol);
      *(uint4*)&Bs[r * 40 + scol] = *(const uint4*)(Bt + (size_t)(n0 + r) * K + k0 + scol);
    }
    __syncthreads();
    bf16x8 af[4], bfr[4];
#pragma unroll
    for (int mt = 0; mt < 4; mt++) af[mt] = *(const bf16x8*)&As[(wr2 * 64 + mt * 16 + r0) * 40 + q * 8];
#pragma unroll
    for (int nt = 0; nt < 4; nt++) bfr[nt] = *(const bf16x8*)&Bs[(wc2 * 64 + nt * 16 + r0) * 40 + q * 8];
#pragma unroll
    for (int mt = 0; mt < 4; mt++)
#pragma unroll
      for (int nt = 0; nt < 4; nt++)
        acc[mt][nt] = mfma16(af[mt], bfr[nt], acc[mt][nt]);
  }
#pragma unroll
  for (int mt = 0; mt < 4; mt++)
#pragma unroll
    for (int nt = 0; nt < 4; nt++)
#pragma unroll
      for (int r = 0; r < 4; r++) {
        int row = m0 + wr2 * 64 + mt * 16 + q * 4 + r;
        int col = n0 + wc2 * 64 + nt * 16 + r0;
        float v = acc[mt][nt][r];
        if (OUT_BF16) ((bf16*)Cout)[(size_t)row * N + col] = (bf16)v;
        else          ((float*)Cout)[(size_t)row * N + col] = v;
      }
}

// ---------------- postproc: gate+ve add, RoPE, RMS, layout for attention ----------------
__global__ void postproc_kernel(const bf16* __restrict__ qkv, const float* __restrict__ x,
                                const float* __restrict__ ve, const float* __restrict__ cosb,
                                const float* __restrict__ sinb, const float* __restrict__ wgate,
                                bf16* __restrict__ Qb, bf16* __restrict__ Kb, bf16* __restrict__ Vb) {
  int t = blockIdx.x;
  int b = t >> 11, s = t & 2047;
  int lane = threadIdx.x;

  // gate = 2*sigmoid(x[:,:128] @ Wgate)  (Wgate: [128][4] row-major)
  float g[4];
  const float* xrow = x + (size_t)t * 1024;
  float x0 = xrow[lane], x1 = xrow[64 + lane];
#pragma unroll
  for (int kv = 0; kv < 4; kv++)
    g[kv] = x0 * wgate[lane * 4 + kv] + x1 * wgate[(64 + lane) * 4 + kv];
#pragma unroll
  for (int kv = 0; kv < 4; kv++) {
    float v = g[kv];
    for (int m = 1; m < 64; m <<= 1) v += __shfl_xor(v, m, 64);
    g[kv] = 2.f / (1.f + __expf(-v));
  }

  int d = lane & 31;
  float c = cosb[s * 32 + d], sn = sinb[s * 32 + d];
  float sgn = (lane < 32) ? sn : -sn;
  const bf16* qrow = qkv + (size_t)t * 1536;

  // q heads: rope -> rms -> * (0.125*log2e) (score scale + exp2 conversion folded in)
  for (int h = 0; h < 16; h++) {
    float v = (float)qrow[h * 64 + lane];
    float p = __shfl_xor(v, 32, 64);
    float rv = v * c + p * sgn;
    float ss = rv * rv;
    for (int m = 1; m < 64; m <<= 1) ss += __shfl_xor(ss, m, 64);
    float outq = rv * rsqrtf(ss * (1.f / 64.f) + EPS) * QSCALE;
    Qb[(((size_t)b * 16 + h) * 2048 + s) * 64 + lane] = (bf16)outq;
  }
  // k heads + v (v gets gate*ve, no rope/rms; coalesced [s][d] layout)
  for (int kv = 0; kv < 4; kv++) {
    float v = (float)qrow[1024 + kv * 64 + lane];
    float p = __shfl_xor(v, 32, 64);
    float rv = v * c + p * sgn;
    float ss = rv * rv;
    for (int m = 1; m < 64; m <<= 1) ss += __shfl_xor(ss, m, 64);
    float outk = rv * rsqrtf(ss * (1.f / 64.f) + EPS);
    Kb[(((size_t)b * 4 + kv) * 2048 + s) * 64 + lane] = (bf16)outk;
    float vv = (float)qrow[1280 + kv * 64 + lane] + g[kv] * ve[(size_t)t * 256 + kv * 64 + lane];
    Vb[(((size_t)b * 4 + kv) * 2048 + s) * 64 + lane] = (bf16)vv;
  }
}

// ---------------- pack K/V into per-32-key-tile lane-ordered fragment layouts ----------------
// Kf tile (2048 bf16): [w][lane][8]  w=0..3: (joff,doff) = (0,0),(0,32),(16,0),(16,32)
//   elem: K[j0 + joff + r0][doff + q*8 + e]
// Vf tile (2048 bf16): [nt][lane][8] elem e: V[j0 + (e>>2)*16 + 4q + (e&3)][nt*16 + r0]
__global__ void pack_kv_kernel(const bf16* __restrict__ Kb, const bf16* __restrict__ Vb,
                               bf16* __restrict__ Kf, bf16* __restrict__ Vf) {
  __shared__ bf16 Ks[64 * 72];
  __shared__ bf16 Vs[64 * 72];
  int chunk = blockIdx.x;  // 64-key chunk
  int bkv = blockIdx.y;
  const bf16* kin = Kb + ((size_t)bkv * 2048 + chunk * 64) * 64;
  const bf16* vin = Vb + ((size_t)bkv * 2048 + chunk * 64) * 64;
  int t = threadIdx.x;
  int row = t >> 3, col = (t & 7) * 8;
#pragma unroll
  for (int i = 0; i < 2; i++) {
    *(uint4*)&Ks[(row + 32 * i) * 72 + col] = *(const uint4*)(kin + (size_t)(row + 32 * i) * 64 + col);
    *(uint4*)&Vs[(row + 32 * i) * 72 + col] = *(const uint4*)(vin + (size_t)(row + 32 * i) * 64 + col);
  }
  __syncthreads();
  int lane = t & 63, q = (t >> 4) & 3, r0 = t & 15;
  int sub = t >> 7;          // tile within chunk
  int pair = (t >> 6) & 1;   // frag pair
  size_t tbase = ((size_t)bkv * 64 + chunk * 2 + sub) * 2048;
#pragma unroll
  for (int i = 0; i < 2; i++) {
    int w = pair * 2 + i;
    int jl = sub * 32 + (w >= 2 ? 16 : 0) + r0;
    int d0 = (w & 1) * 32 + q * 8;
    *(uint4*)&Kf[tbase + w * 512 + lane * 8] = *(const uint4*)&Ks[jl * 72 + d0];
  }
#pragma unroll
  for (int i = 0; i < 2; i++) {
    int nt = pair * 2 + i;
    int d = nt * 16 + r0;
    bf16 tmp[8];
#pragma unroll
    for (int e = 0; e < 8; e++) {
      int jl = sub * 32 + (e >> 2) * 16 + 4 * q + (e & 3);
      tmp[e] = Vs[jl * 72 + d];
    }
    *(uint4*)&Vf[tbase + nt * 512 + lane * 8] = *(uint4*)tmp;
  }
}

// ---------------- flash attention: transposed-S, coalesced frags, split-j, prefetch ----------------
__global__ __launch_bounds__(512, 4) void attn_kernel(const bf16* __restrict__ Qb,
                                                      const bf16* __restrict__ Kf,
                                                      const bf16* __restrict__ Vf,
                                                      const int* __restrict__ wlp,
                                                      const int* __restrict__ wrp,
                                                      bf16* __restrict__ Yb) {
  __shared__ float Ol[4 * 64 * 21];  // upper-half partials: [wq][lane][16 O + 4 L], stride 21
  const int wl = wlp[0];
  const int wrc = min(wrp[0], 0);  // j<=i+wr && j<=i  ==>  j <= i+min(wr,0)
  const int blk = blockIdx.x;
  const int qc = 31 - (blk & 31);  // reversed: longest blocks launch first
  const int bh = blk >> 5;
  const int b = bh >> 4, h = bh & 15, kvh = (bh & 15) >> 2;
  const int w = threadIdx.x >> 6, lane = threadIdx.x & 63;
  const int wq = w & 3, jh = w >> 2;
  const int q = lane >> 4, r0 = lane & 15;
  const int q0 = qc * 64 + wq * 16;

  const bf16* qbase = Qb + (((size_t)b * 16 + h) * 2048 + q0 + r0) * 64;
  bf16x8 aq0 = *(const bf16x8*)(qbase + q * 8);
  bf16x8 aq1 = *(const bf16x8*)(qbase + 32 + q * 8);

  floatx4 Oacc[4];
#pragma unroll
  for (int nt = 0; nt < 4; nt++) Oacc[nt] = (floatx4){0.f, 0.f, 0.f, 0.f};
  floatx4 Lacc = (floatx4){0.f, 0.f, 0.f, 0.f};

  const bf16 onev = (bf16)1.0f;
  const bf16x8 ones = {onev, onev, onev, onev, onev, onev, onev, onev};

  const int jlo0 = max(0, q0 - wl) & ~31;
  const int jhi = q0 + 15 + wrc;
  const int n = ((jhi - jlo0) >> 5) + 1;
  const int nlo = (n + 1) >> 1;
  const int jstart = jh ? jlo0 + (nlo << 5) : jlo0;
  const int count = jh ? n - nlo : nlo;

  const bf16* kfb = Kf + ((size_t)(b * 4 + kvh) * 64) * 2048 + lane * 8;
  const bf16* vfb = Vf + ((size_t)(b * 4 + kvh) * 64) * 2048 + lane * 8;

  if (count > 0) {
    int tile0 = jstart >> 5;
    bf16x8 kf[4], vf[4], nk[4], nv[4];
#pragma unroll
    for (int u = 0; u < 4; u++) {
      kf[u] = *(const bf16x8*)(kfb + (size_t)tile0 * 2048 + u * 512);
      vf[u] = *(const bf16x8*)(vfb + (size_t)tile0 * 2048 + u * 512);
    }

    for (int t = 0; t < count; t++) {
      const int j0 = jstart + (t << 5);
      // prefetch next tile (re-load current on last iter)
      const int tn = (t + 1 < count) ? tile0 + t + 1 : tile0 + t;
#pragma unroll
      for (int u = 0; u < 4; u++) {
        nk[u] = *(const bf16x8*)(kfb + (size_t)tn * 2048 + u * 512);
        nv[u] = *(const bf16x8*)(vfb + (size_t)tn * 2048 + u * 512);
      }

      // St = K·Q^T - SHIFT_C  (C-layout: row j-j0 = 4q+r (+16*sub), col i-q0 = r0)
      floatx4 s0 = (floatx4){-SHIFT_C, -SHIFT_C, -SHIFT_C, -SHIFT_C};
      floatx4 s1 = s0;
      s0 = mfma16(kf[0], aq0, s0);
      s0 = mfma16(kf[1], aq1, s0);
      s1 = mfma16(kf[2], aq0, s1);
      s1 = mfma16(kf[3], aq1, s1);

      bf16x8 pa;
      if (j0 >= q0 + 15 - wl && j0 + 31 <= q0 + wrc) {
#pragma unroll
        for (int r = 0; r < 4; r++) {
          pa[r] = (bf16)exp2f(s0[r]);
          pa[4 + r] = (bf16)exp2f(s1[r]);
        }
      } else {
        const int i = q0 + r0;
#pragma unroll
        for (int r = 0; r < 4; r++) {
          int ja = j0 + 4 * q + r, jb = ja + 16;
          bool va = (ja <= i + wrc) && (ja >= i - wl);
          bool vb = (jb <= i + wrc) && (jb >= i - wl);
          pa[r] = va ? (bf16)exp2f(s0[r]) : (bf16)0.f;
          pa[4 + r] = vb ? (bf16)exp2f(s1[r]) : (bf16)0.f;
        }
      }

      Lacc = mfma16(pa, ones, Lacc);
#pragma unroll
      for (int nt = 0; nt < 4; nt++) Oacc[nt] = mfma16(pa, vf[nt], Oacc[nt]);

#pragma unroll
      for (int u = 0; u < 4; u++) { kf[u] = nk[u]; vf[u] = nv[u]; }
    }
  }

  // merge the two j-halves: upper waves deposit partials, lower waves combine + write
  float* mbase = Ol + (wq * 64 + lane) * 21;
  if (jh == 1) {
#pragma unroll
    for (int nt = 0; nt < 4; nt++)
#pragma unroll
      for (int r = 0; r < 4; r++) mbase[nt * 4 + r] = Oacc[nt][r];
#pragma unroll
    for (int r = 0; r < 4; r++) mbase[16 + r] = Lacc[r];
  }
  __syncthreads();
  if (jh == 0) {
    float inv[4];
#pragma unroll
    for (int r = 0; r < 4; r++) inv[r] = 1.f / (Lacc[r] + mbase[16 + r]);
#pragma unroll
    for (int nt = 0; nt < 4; nt++)
#pragma unroll
      for (int r = 0; r < 4; r++) {
        int i = q0 + q * 4 + r;
        float o = (Oacc[nt][r] + mbase[nt * 4 + r]) * inv[r];
        Yb[((size_t)b * 2048 + i) * 1024 + h * 64 + nt * 16 + r0] = (bf16)o;
      }
  }
}

// ---------------- launch ----------------
extern "C" void kernel_launch(void* const* d_in, const int* in_sizes, int n_in,
                              void* d_out, int out_size, void* d_ws, size_t ws_size,
                              hipStream_t stream) {
  const float* x     = (const float*)d_in[0];
  const float* ve    = (const float*)d_in[1];
  const float* cosb  = (const float*)d_in[2];
  const float* sinb  = (const float*)d_in[3];
  const float* Wq    = (const float*)d_in[4];
  const float* Wk    = (const float*)d_in[5];
  const float* Wv    = (const float*)d_in[6];
  const float* Wproj = (const float*)d_in[7];
  const float* Wgate = (const float*)d_in[8];
  const int* wl      = (const int*)d_in[9];
  const int* wr      = (const int*)d_in[10];

  char* ws = (char*)d_ws;
  bf16* Xb      = (bf16*)(ws);                 //  8,388,608 B: x bf16 [4096][1024]
  bf16* Wqkv_t  = (bf16*)(ws + 8388608);       //  3,145,728 B: [1536][1024]
  bf16* Wproj_t = (bf16*)(ws + 11534336);      //  2,097,152 B: [1024][1024]
  bf16* qkvb    = (bf16*)(ws + 13631488);      // 12,582,912 B: [4096][1536]
  bf16* Qb      = (bf16*)(ws + 26214400);      //  8,388,608 B: [2][16][2048][64]
  bf16* Kb      = (bf16*)(ws + 34603008);      //  2,097,152 B: [2][4][2048][64]
  bf16* Kf      = (bf16*)(ws + 36700160);      //  2,097,152 B: frag K [8][64 tiles][2048]
  bf16* Yb      = (bf16*)(ws + 38797312);      //  8,388,608 B: [4096][1024]
  bf16* Vb      = Yb;                          //  2 MB staging inside Yb (dead before attn)
  bf16* Vf      = qkvb;                        //  2 MB inside dead qkvb (dead after postproc)

  cast_x_kernel<<<4096, 256, 0, stream>>>(x, Xb);
  pack_wqkv_kernel<<<dim3(48, 32), 256, 0, stream>>>(Wq, Wk, Wv, Wqkv_t);
  trans_wproj_kernel<<<dim3(32, 32), 256, 0, stream>>>(Wproj, Wproj_t);
  gemm_kernel<true><<<dim3(12, 32), 256, 0, stream>>>(Xb, Wqkv_t, qkvb, 4096, 1536, 1024);
  postproc_kernel<<<4096, 64, 0, stream>>>(qkvb, x, ve, cosb, sinb, Wgate, Qb, Kb, Vb);
  pack_kv_kernel<<<dim3(32, 8), 256, 0, stream>>>(Kb, Vb, Kf, Vf);
  attn_kernel<<<1024, 512, 0, stream>>>(Qb, Kf, Vf, wl, wr, Yb);
  gemm_kernel<false><<<dim3(8, 32), 256, 0, stream>>>(Yb, Wproj_t, d_out, 4096, 1024, 1024);
}

// Round 5
// 198.440 us; speedup vs baseline: 1.7455x; 1.0533x over previous
//
#include <hip/hip_runtime.h>

typedef __bf16 bf16;
typedef __bf16 bf16x4 __attribute__((ext_vector_type(4)));
typedef __bf16 bf16x8 __attribute__((ext_vector_type(8)));
typedef float floatx4 __attribute__((ext_vector_type(4)));

#define EPS 1.1920929e-07f
// q scale = D^-0.5 * log2(e) folded together (D=64 -> 0.125)
#define QSCALE (0.125f * 1.44269504088896f)
// fixed softmax shift: |q_eff . k| <= ||q_eff||*||k|| = (8*QSCALE)*8 = 11.5416
#define SHIFT_C 11.5416f

__device__ __forceinline__ floatx4 mfma16(bf16x8 a, bf16x8 b, floatx4 c) {
  return __builtin_amdgcn_mfma_f32_16x16x32_bf16(a, b, c, 0, 0, 0);
}

// async 16B global->LDS: HW writes ldsbase + lane*16; gptr is per-lane
__device__ __forceinline__ void gload16(const void* g, void* l) {
  __builtin_amdgcn_global_load_lds((const __attribute__((address_space(1))) unsigned int*)g,
                                   (__attribute__((address_space(3))) unsigned int*)l, 16, 0, 0);
}

// ---------------- prep kernels ----------------
__global__ void cast_x_kernel(const float* __restrict__ x, bf16* __restrict__ xb) {
  int i = (blockIdx.x * blockDim.x + threadIdx.x) * 4;
  float4 v = *(const float4*)(x + i);
  bf16x4 o = {(bf16)v.x, (bf16)v.y, (bf16)v.z, (bf16)v.w};
  *(bf16x4*)(xb + i) = o;
}

// Wqkv_t[n][k] (n<1024: Wq col n; n<1280: Wk col n-1024; else Wv col n-1280), bf16
__global__ void pack_wqkv_kernel(const float* __restrict__ Wq, const float* __restrict__ Wk,
                                 const float* __restrict__ Wv, bf16* __restrict__ out) {
  __shared__ float tile[32][33];
  int n0 = blockIdx.x * 32, k0 = blockIdx.y * 32;
  int tx = threadIdx.x & 31, ty = threadIdx.x >> 5;
#pragma unroll
  for (int i = 0; i < 4; i++) {
    int k = k0 + ty + i * 8, n = n0 + tx;
    float v;
    if (n < 1024)      v = Wq[(size_t)k * 1024 + n];
    else if (n < 1280) v = Wk[(size_t)k * 256 + (n - 1024)];
    else               v = Wv[(size_t)k * 256 + (n - 1280)];
    tile[ty + i * 8][tx] = v;
  }
  __syncthreads();
#pragma unroll
  for (int i = 0; i < 4; i++) {
    int n = n0 + ty + i * 8, k = k0 + tx;
    out[(size_t)n * 1024 + k] = (bf16)tile[tx][ty + i * 8];
  }
}

__global__ void trans_wproj_kernel(const float* __restrict__ W, bf16* __restrict__ out) {
  __shared__ float tile[32][33];
  int n0 = blockIdx.x * 32, k0 = blockIdx.y * 32;
  int tx = threadIdx.x & 31, ty = threadIdx.x >> 5;
#pragma unroll
  for (int i = 0; i < 4; i++)
    tile[ty + i * 8][tx] = W[(size_t)(k0 + ty + i * 8) * 1024 + n0 + tx];
  __syncthreads();
#pragma unroll
  for (int i = 0; i < 4; i++)
    out[(size_t)(n0 + ty + i * 8) * 1024 + k0 + tx] = (bf16)tile[tx][ty + i * 8];
}

// ---------------- GEMM 128m x 64n tiles, global_load_lds staging (m97 structure) --------
// C[M][N] = A[M][K] * Bt[N][K]^T, bf16 in, fp32 acc
template <bool OUT_BF16>
__global__ __launch_bounds__(256) void gemm_kernel(const bf16* __restrict__ A,
                                                   const bf16* __restrict__ Bt,
                                                   void* __restrict__ Cout,
                                                   int M, int N, int K) {
  __shared__ bf16 As[128 * 32];  // [row][32] unpadded, exact lane order for load_lds
  __shared__ bf16 Bs[64 * 32];
  const int tid = threadIdx.x;
  const int m0 = blockIdx.y * 128, n0 = blockIdx.x * 64;
  const int w = tid >> 6, lane = tid & 63;
  const int q = lane >> 4, r0 = lane & 15;
  const int wm = w & 1, wn = w >> 1;          // wave covers 64m x 32n
  const int lrow = lane >> 2, lcol = (lane & 3) * 8;

  floatx4 acc[4][2];
#pragma unroll
  for (int i = 0; i < 4; i++)
#pragma unroll
    for (int j = 0; j < 2; j++) acc[i][j] = (floatx4){0.f, 0.f, 0.f, 0.f};

  for (int k0 = 0; k0 < K; k0 += 32) {
    __syncthreads();
    // A: 128 rows; wave w issues rows {w*16, 64+w*16}; B: 64 rows; wave w issues rows w*16
    gload16(A + (size_t)(m0 + w * 16 + lrow) * K + k0 + lcol, &As[(w * 16) * 32]);
    gload16(A + (size_t)(m0 + 64 + w * 16 + lrow) * K + k0 + lcol, &As[(64 + w * 16) * 32]);
    gload16(Bt + (size_t)(n0 + w * 16 + lrow) * K + k0 + lcol, &Bs[(w * 16) * 32]);
    __syncthreads();
    bf16x8 af[4], bfr[2];
#pragma unroll
    for (int mt = 0; mt < 4; mt++) af[mt] = *(const bf16x8*)&As[(wm * 64 + mt * 16 + r0) * 32 + q * 8];
#pragma unroll
    for (int nt = 0; nt < 2; nt++) bfr[nt] = *(const bf16x8*)&Bs[(wn * 32 + nt * 16 + r0) * 32 + q * 8];
#pragma unroll
    for (int mt = 0; mt < 4; mt++)
#pragma unroll
      for (int nt = 0; nt < 2; nt++)
        acc[mt][nt] = mfma16(af[mt], bfr[nt], acc[mt][nt]);
  }
#pragma unroll
  for (int mt = 0; mt < 4; mt++)
#pragma unroll
    for (int nt = 0; nt < 2; nt++)
#pragma unroll
      for (int r = 0; r < 4; r++) {
        int row = m0 + wm * 64 + mt * 16 + q * 4 + r;
        int col = n0 + wn * 32 + nt * 16 + r0;
        float v = acc[mt][nt][r];
        if (OUT_BF16) ((bf16*)Cout)[(size_t)row * N + col] = (bf16)v;
        else          ((float*)Cout)[(size_t)row * N + col] = v;
      }
}

// ---------------- postproc: 4 waves/token; wave w: q-heads 4w..4w+3, kv-head w ----------
__global__ void postproc_kernel(const bf16* __restrict__ qkv, const float* __restrict__ x,
                                const float* __restrict__ ve, const float* __restrict__ cosb,
                                const float* __restrict__ sinb, const float* __restrict__ wgate,
                                bf16* __restrict__ Qb, bf16* __restrict__ Kb, bf16* __restrict__ Vb) {
  int t = blockIdx.x;
  int b = t >> 11, s = t & 2047;
  int w = threadIdx.x >> 6, lane = threadIdx.x & 63;

  // gate for kv-head w: 2*sigmoid(x[:128] . Wgate[:,w])
  const float* xrow = x + (size_t)t * 1024;
  float g = xrow[lane] * wgate[lane * 4 + w] + xrow[64 + lane] * wgate[(64 + lane) * 4 + w];
  for (int m = 1; m < 64; m <<= 1) g += __shfl_xor(g, m, 64);
  g = 2.f / (1.f + __expf(-g));

  int d = lane & 31;
  float c = cosb[s * 32 + d], sn = sinb[s * 32 + d];
  float sgn = (lane < 32) ? sn : -sn;
  const bf16* qrow = qkv + (size_t)t * 1536;

  // 4 q heads: rope -> rms -> * (0.125*log2e)
#pragma unroll
  for (int i = 0; i < 4; i++) {
    int h = w * 4 + i;
    float v = (float)qrow[h * 64 + lane];
    float p = __shfl_xor(v, 32, 64);
    float rv = v * c + p * sgn;
    float ss = rv * rv;
    for (int m = 1; m < 64; m <<= 1) ss += __shfl_xor(ss, m, 64);
    float outq = rv * rsqrtf(ss * (1.f / 64.f) + EPS) * QSCALE;
    Qb[(((size_t)b * 16 + h) * 2048 + s) * 64 + lane] = (bf16)outq;
  }
  // k + v for kv-head w
  {
    float v = (float)qrow[1024 + w * 64 + lane];
    float p = __shfl_xor(v, 32, 64);
    float rv = v * c + p * sgn;
    float ss = rv * rv;
    for (int m = 1; m < 64; m <<= 1) ss += __shfl_xor(ss, m, 64);
    float outk = rv * rsqrtf(ss * (1.f / 64.f) + EPS);
    Kb[(((size_t)b * 4 + w) * 2048 + s) * 64 + lane] = (bf16)outk;
    float vv = (float)qrow[1280 + w * 64 + lane] + g * ve[(size_t)t * 256 + w * 64 + lane];
    Vb[(((size_t)b * 4 + w) * 2048 + s) * 64 + lane] = (bf16)vv;
  }
}

// ---------------- pack K/V into per-32-key-tile lane-ordered fragment layouts ----------------
// Kf tile (2048 bf16): [w][lane][8]  w=0..3: (joff,doff) = (0,0),(0,32),(16,0),(16,32)
//   elem: K[j0 + joff + r0][doff + q*8 + e]
// Vf tile (2048 bf16): [nt][lane][8] elem e: V[j0 + (e>>2)*16 + 4q + (e&3)][nt*16 + r0]
__global__ void pack_kv_kernel(const bf16* __restrict__ Kb, const bf16* __restrict__ Vb,
                               bf16* __restrict__ Kf, bf16* __restrict__ Vf) {
  __shared__ bf16 Ks[64 * 72];
  __shared__ bf16 Vs[64 * 72];
  int chunk = blockIdx.x;  // 64-key chunk
  int bkv = blockIdx.y;
  const bf16* kin = Kb + ((size_t)bkv * 2048 + chunk * 64) * 64;
  const bf16* vin = Vb + ((size_t)bkv * 2048 + chunk * 64) * 64;
  int t = threadIdx.x;
  int row = t >> 3, col = (t & 7) * 8;
#pragma unroll
  for (int i = 0; i < 2; i++) {
    *(uint4*)&Ks[(row + 32 * i) * 72 + col] = *(const uint4*)(kin + (size_t)(row + 32 * i) * 64 + col);
    *(uint4*)&Vs[(row + 32 * i) * 72 + col] = *(const uint4*)(vin + (size_t)(row + 32 * i) * 64 + col);
  }
  __syncthreads();
  int lane = t & 63, q = (t >> 4) & 3, r0 = t & 15;
  int sub = t >> 7;          // tile within chunk
  int pair = (t >> 6) & 1;   // frag pair
  size_t tbase = ((size_t)bkv * 64 + chunk * 2 + sub) * 2048;
#pragma unroll
  for (int i = 0; i < 2; i++) {
    int w = pair * 2 + i;
    int jl = sub * 32 + (w >= 2 ? 16 : 0) + r0;
    int d0 = (w & 1) * 32 + q * 8;
    *(uint4*)&Kf[tbase + w * 512 + lane * 8] = *(const uint4*)&Ks[jl * 72 + d0];
  }
#pragma unroll
  for (int i = 0; i < 2; i++) {
    int nt = pair * 2 + i;
    int d = nt * 16 + r0;
    bf16 tmp[8];
#pragma unroll
    for (int e = 0; e < 8; e++) {
      int jl = sub * 32 + (e >> 2) * 16 + 4 * q + (e & 3);
      tmp[e] = Vs[jl * 72 + d];
    }
    *(uint4*)&Vf[tbase + nt * 512 + lane * 8] = *(uint4*)tmp;
  }
}

// ---------------- flash attention: transposed-S, coalesced frags, split-j, prefetch ----------------
__global__ __launch_bounds__(512, 4) void attn_kernel(const bf16* __restrict__ Qb,
                                                      const bf16* __restrict__ Kf,
                                                      const bf16* __restrict__ Vf,
                                                      const int* __restrict__ wlp,
                                                      const int* __restrict__ wrp,
                                                      bf16* __restrict__ Yb) {
  __shared__ float Ol[4 * 64 * 21];  // upper-half partials: [wq][lane][16 O + 4 L], stride 21
  const int wl = wlp[0];
  const int wrc = min(wrp[0], 0);  // j<=i+wr && j<=i  ==>  j <= i+min(wr,0)
  const int blk = blockIdx.x;
  const int qc = 31 - (blk & 31);  // reversed: longest blocks launch first
  const int bh = blk >> 5;
  const int b = bh >> 4, h = bh & 15, kvh = (bh & 15) >> 2;
  const int w = threadIdx.x >> 6, lane = threadIdx.x & 63;
  const int wq = w & 3, jh = w >> 2;
  const int q = lane >> 4, r0 = lane & 15;
  const int q0 = qc * 64 + wq * 16;

  const bf16* qbase = Qb + (((size_t)b * 16 + h) * 2048 + q0 + r0) * 64;
  bf16x8 aq0 = *(const bf16x8*)(qbase + q * 8);
  bf16x8 aq1 = *(const bf16x8*)(qbase + 32 + q * 8);

  floatx4 Oacc[4];
#pragma unroll
  for (int nt = 0; nt < 4; nt++) Oacc[nt] = (floatx4){0.f, 0.f, 0.f, 0.f};
  floatx4 Lacc = (floatx4){0.f, 0.f, 0.f, 0.f};

  const bf16 onev = (bf16)1.0f;
  const bf16x8 ones = {onev, onev, onev, onev, onev, onev, onev, onev};

  const int jlo0 = max(0, q0 - wl) & ~31;
  const int jhi = q0 + 15 + wrc;
  const int n = ((jhi - jlo0) >> 5) + 1;
  const int nlo = (n + 1) >> 1;
  const int jstart = jh ? jlo0 + (nlo << 5) : jlo0;
  const int count = jh ? n - nlo : nlo;

  const bf16* kfb = Kf + ((size_t)(b * 4 + kvh) * 64) * 2048 + lane * 8;
  const bf16* vfb = Vf + ((size_t)(b * 4 + kvh) * 64) * 2048 + lane * 8;

  if (count > 0) {
    int tile0 = jstart >> 5;
    bf16x8 kf[4], vf[4], nk[4], nv[4];
#pragma unroll
    for (int u = 0; u < 4; u++) {
      kf[u] = *(const bf16x8*)(kfb + (size_t)tile0 * 2048 + u * 512);
      vf[u] = *(const bf16x8*)(vfb + (size_t)tile0 * 2048 + u * 512);
    }

    for (int t = 0; t < count; t++) {
      const int j0 = jstart + (t << 5);
      // prefetch next tile (re-load current on last iter)
      const int tn = (t + 1 < count) ? tile0 + t + 1 : tile0 + t;
#pragma unroll
      for (int u = 0; u < 4; u++) {
        nk[u] = *(const bf16x8*)(kfb + (size_t)tn * 2048 + u * 512);
        nv[u] = *(const bf16x8*)(vfb + (size_t)tn * 2048 + u * 512);
      }

      // St = K·Q^T - SHIFT_C  (C-layout: row j-j0 = 4q+r (+16*sub), col i-q0 = r0)
      floatx4 s0 = (floatx4){-SHIFT_C, -SHIFT_C, -SHIFT_C, -SHIFT_C};
      floatx4 s1 = s0;
      s0 = mfma16(kf[0], aq0, s0);
      s0 = mfma16(kf[1], aq1, s0);
      s1 = mfma16(kf[2], aq0, s1);
      s1 = mfma16(kf[3], aq1, s1);

      bf16x8 pa;
      if (j0 >= q0 + 15 - wl && j0 + 31 <= q0 + wrc) {
#pragma unroll
        for (int r = 0; r < 4; r++) {
          pa[r] = (bf16)exp2f(s0[r]);
          pa[4 + r] = (bf16)exp2f(s1[r]);
        }
      } else {
        const int i = q0 + r0;
#pragma unroll
        for (int r = 0; r < 4; r++) {
          int ja = j0 + 4 * q + r, jb = ja + 16;
          bool va = (ja <= i + wrc) && (ja >= i - wl);
          bool vb = (jb <= i + wrc) && (jb >= i - wl);
          pa[r] = va ? (bf16)exp2f(s0[r]) : (bf16)0.f;
          pa[4 + r] = vb ? (bf16)exp2f(s1[r]) : (bf16)0.f;
        }
      }

      Lacc = mfma16(pa, ones, Lacc);
#pragma unroll
      for (int nt = 0; nt < 4; nt++) Oacc[nt] = mfma16(pa, vf[nt], Oacc[nt]);

#pragma unroll
      for (int u = 0; u < 4; u++) { kf[u] = nk[u]; vf[u] = nv[u]; }
    }
  }

  // merge the two j-halves: upper waves deposit partials, lower waves combine + write
  float* mbase = Ol + (wq * 64 + lane) * 21;
  if (jh == 1) {
#pragma unroll
    for (int nt = 0; nt < 4; nt++)
#pragma unroll
      for (int r = 0; r < 4; r++) mbase[nt * 4 + r] = Oacc[nt][r];
#pragma unroll
    for (int r = 0; r < 4; r++) mbase[16 + r] = Lacc[r];
  }
  __syncthreads();
  if (jh == 0) {
    float inv[4];
#pragma unroll
    for (int r = 0; r < 4; r++) inv[r] = 1.f / (Lacc[r] + mbase[16 + r]);
#pragma unroll
    for (int nt = 0; nt < 4; nt++)
#pragma unroll
      for (int r = 0; r < 4; r++) {
        int i = q0 + q * 4 + r;
        float o = (Oacc[nt][r] + mbase[nt * 4 + r]) * inv[r];
        Yb[((size_t)b * 2048 + i) * 1024 + h * 64 + nt * 16 + r0] = (bf16)o;
      }
  }
}

// ---------------- launch ----------------
extern "C" void kernel_launch(void* const* d_in, const int* in_sizes, int n_in,
                              void* d_out, int out_size, void* d_ws, size_t ws_size,
                              hipStream_t stream) {
  const float* x     = (const float*)d_in[0];
  const float* ve    = (const float*)d_in[1];
  const float* cosb  = (const float*)d_in[2];
  const float* sinb  = (const float*)d_in[3];
  const float* Wq    = (const float*)d_in[4];
  const float* Wk    = (const float*)d_in[5];
  const float* Wv    = (const float*)d_in[6];
  const float* Wproj = (const float*)d_in[7];
  const float* Wgate = (const float*)d_in[8];
  const int* wl      = (const int*)d_in[9];
  const int* wr      = (const int*)d_in[10];

  char* ws = (char*)d_ws;
  bf16* Xb      = (bf16*)(ws);                 //  8,388,608 B: x bf16 [4096][1024]
  bf16* Wqkv_t  = (bf16*)(ws + 8388608);       //  3,145,728 B: [1536][1024]
  bf16* Wproj_t = (bf16*)(ws + 11534336);      //  2,097,152 B: [1024][1024]
  bf16* qkvb    = (bf16*)(ws + 13631488);      // 12,582,912 B: [4096][1536]
  bf16* Qb      = (bf16*)(ws + 26214400);      //  8,388,608 B: [2][16][2048][64]
  bf16* Kb      = (bf16*)(ws + 34603008);      //  2,097,152 B: [2][4][2048][64]
  bf16* Kf      = (bf16*)(ws + 36700160);      //  2,097,152 B: frag K [8][64 tiles][2048]
  bf16* Yb      = (bf16*)(ws + 38797312);      //  8,388,608 B: [4096][1024]
  bf16* Vb      = Yb;                          //  2 MB staging inside Yb (dead before attn)
  bf16* Vf      = qkvb;                        //  2 MB inside dead qkvb (dead after postproc)

  cast_x_kernel<<<4096, 256, 0, stream>>>(x, Xb);
  pack_wqkv_kernel<<<dim3(48, 32), 256, 0, stream>>>(Wq, Wk, Wv, Wqkv_t);
  trans_wproj_kernel<<<dim3(32, 32), 256, 0, stream>>>(Wproj, Wproj_t);
  gemm_kernel<true><<<dim3(24, 32), 256, 0, stream>>>(Xb, Wqkv_t, qkvb, 4096, 1536, 1024);
  postproc_kernel<<<4096, 256, 0, stream>>>(qkvb, x, ve, cosb, sinb, Wgate, Qb, Kb, Vb);
  pack_kv_kernel<<<dim3(32, 8), 256, 0, stream>>>(Kb, Vb, Kf, Vf);
  attn_kernel<<<1024, 512, 0, stream>>>(Qb, Kf, Vf, wl, wr, Yb);
  gemm_kernel<false><<<dim3(16, 32), 256, 0, stream>>>(Yb, Wproj_t, d_out, 4096, 1024, 1024);
}